// Round 2
// baseline (733.029 us; speedup 1.0000x reference)
//
#include <hip/hip_runtime.h>
#include <hip/hip_bf16.h>

#define DEV __device__ __forceinline__

typedef __attribute__((ext_vector_type(8))) short short8;
typedef __attribute__((ext_vector_type(4))) float f32x4;

constexpr int NTOK = 8192;   // B*L
constexpr int DIM  = 1024;   // D
constexpr int FF   = 2048;   // F
constexpr int NE   = 8;      // experts
constexpr int BM = 128, BN = 128, BK = 64;

// ---------------- async global->LDS, 16B per lane ----------------
DEV void async_copy16(const void* g, void* l) {
  __builtin_amdgcn_global_load_lds(
      (const __attribute__((address_space(1))) unsigned int*)g,
      (__attribute__((address_space(3))) unsigned int*)l, 16, 0, 0);
}

DEV float silu_f(float v) { return v / (1.f + __expf(-v)); }

// ---------------- x fp32 -> bf16, 8 elems/thread ----------------
__global__ void k_convx(const float* __restrict__ x, __hip_bfloat16* __restrict__ xb) {
  size_t i = (size_t)blockIdx.x * blockDim.x + threadIdx.x;  // one per 8 elements
  const float4* s = (const float4*)x + i * 2;
  float4 a = s[0], b = s[1];
  __hip_bfloat16 tmp[8];
  tmp[0] = __float2bfloat16(a.x); tmp[1] = __float2bfloat16(a.y);
  tmp[2] = __float2bfloat16(a.z); tmp[3] = __float2bfloat16(a.w);
  tmp[4] = __float2bfloat16(b.x); tmp[5] = __float2bfloat16(b.y);
  tmp[6] = __float2bfloat16(b.z); tmp[7] = __float2bfloat16(b.w);
  *(short8*)(xb + i * 8) = *(const short8*)tmp;
}

// ---------- transpose-convert: src [R][C] fp32 -> dst [C][R] bf16, per expert z ----------
__global__ void k_tconv(const float* __restrict__ src, __hip_bfloat16* __restrict__ dst,
                        int R, int C) {
  const size_t esz = (size_t)R * C;
  src += esz * blockIdx.z;
  dst += esz * blockIdx.z;
  __shared__ float tile[32][33];            // +1 pad: conflict-free transpose
  const int t = threadIdx.x;
  const int r0 = blockIdx.y * 32, c0 = blockIdx.x * 32;
#pragma unroll
  for (int i = 0; i < 4; ++i) {
    int lr = i * 8 + (t >> 5), lc = t & 31;
    tile[lr][lc] = src[(size_t)(r0 + lr) * C + c0 + lc];
  }
  __syncthreads();
#pragma unroll
  for (int i = 0; i < 4; ++i) {
    int cc = i * 8 + (t >> 5), rr = t & 31;
    dst[(size_t)(c0 + cc) * R + r0 + rr] = __float2bfloat16(tile[rr][cc]);
  }
}

// ---------------- router: fp32 logits, top-2, softmax, compaction ----------------
// fp32 on purpose: top-k selection is discrete; bf16 logits could flip expert choice.
__global__ void k_router(const float* __restrict__ x, const float* __restrict__ gw,
                         float* __restrict__ logits, int* __restrict__ slot_token,
                         float* __restrict__ slot_w, int* __restrict__ counts) {
  const int wave = threadIdx.x >> 6, lane = threadIdx.x & 63;
  const int tok = blockIdx.x * 4 + wave;
  float acc[NE];
#pragma unroll
  for (int e = 0; e < NE; ++e) acc[e] = 0.f;
  const float* xr = x + (size_t)tok * DIM;
  for (int i = 0; i < DIM / 64; ++i) {
    int d = i * 64 + lane;
    float xv = xr[d];
    const float4* g = (const float4*)(gw + (size_t)d * NE);
    float4 g0 = g[0], g1 = g[1];
    acc[0] += xv * g0.x; acc[1] += xv * g0.y; acc[2] += xv * g0.z; acc[3] += xv * g0.w;
    acc[4] += xv * g1.x; acc[5] += xv * g1.y; acc[6] += xv * g1.z; acc[7] += xv * g1.w;
  }
#pragma unroll
  for (int e = 0; e < NE; ++e) {
#pragma unroll
    for (int off = 32; off; off >>= 1) acc[e] += __shfl_xor(acc[e], off);
  }
  if (lane == 0) {
#pragma unroll
    for (int e = 0; e < NE; ++e) logits[(size_t)tok * NE + e] = acc[e];
    // top-2, JAX tie-break (lowest index first) via strict >
    int i0 = 0; float m0 = acc[0];
#pragma unroll
    for (int e = 1; e < NE; ++e) if (acc[e] > m0) { m0 = acc[e]; i0 = e; }
    int i1 = -1; float m1 = -3.4e38f;
#pragma unroll
    for (int e = 0; e < NE; ++e) if (e != i0 && acc[e] > m1) { m1 = acc[e]; i1 = e; }
    float p  = __expf(m1 - m0);           // <= 1
    float wA = 1.f / (1.f + p);           // softmax over the 2 selected logits
    float wB = p * wA;
    int p0 = atomicAdd(&counts[i0], 1);
    slot_token[i0 * NTOK + p0] = tok; slot_w[i0 * NTOK + p0] = wA;
    int p1 = atomicAdd(&counts[i1], 1);
    slot_token[i1 * NTOK + p1] = tok; slot_w[i1 * NTOK + p1] = wB;
  }
}

__global__ void k_scan(const int* __restrict__ counts, int* __restrict__ offsets) {
  if (threadIdx.x == 0) {
    int s = 0;
    for (int e = 0; e < NE; ++e) { offsets[e] = s; s += counts[e]; }
  }
}

// ---------------- expert up-proj: h = silu(x@w1) * (x@w3), gathered rows ----------------
// m97 structure: single-buffer LDS, global_load_lds w16, XOR-swizzled (T2),
// 128x128 tile, 4 waves, 16x16x32 bf16 MFMA. Two B operands share the A tile.
__global__ __launch_bounds__(256, 2) void k_expert_up(
    const __hip_bfloat16* __restrict__ xb,    // [NTOK][DIM]
    const __hip_bfloat16* __restrict__ w1t,   // [E][FF][DIM]  (n-major)
    const __hip_bfloat16* __restrict__ w3t,   // [E][FF][DIM]
    const int* __restrict__ slot_token, const int* __restrict__ counts,
    const int* __restrict__ offsets,
    __hip_bfloat16* __restrict__ h)           // [2*NTOK][FF] compact
{
  const int e  = blockIdx.z;
  const int cnt = counts[e];
  const int m0 = blockIdx.y * BM;
  if (m0 >= cnt) return;
  const int n0 = blockIdx.x * BN;
  const int tid = threadIdx.x, lane = tid & 63, wave = tid >> 6;
  const int wrow = (wave >> 1) * 64, wcol = (wave & 1) * 64;

  __shared__ __hip_bfloat16 sA[BM * BK];
  __shared__ __hip_bfloat16 sB1[BN * BK];
  __shared__ __hip_bfloat16 sB3[BN * BK];

  const int srow = tid >> 3, scol = tid & 7;
  const int swz = scol ^ (srow & 7);          // T2: source-side pre-swizzle (m173)

  const int* stok = slot_token + e * NTOK;
  const __hip_bfloat16* b1e = w1t + (size_t)e * FF * DIM;
  const __hip_bfloat16* b3e = w3t + (size_t)e * FF * DIM;

  const __hip_bfloat16 *gA[4], *gB1[4], *gB3[4];
#pragma unroll
  for (int i = 0; i < 4; ++i) {
    int r = i * 32 + srow;
    int idx = m0 + r;
    int tokv = (idx < cnt) ? stok[idx] : 0;   // clamp padded rows to a valid token
    gA[i]  = xb  + (size_t)tokv * DIM + swz * 8;
    gB1[i] = b1e + (size_t)(n0 + r) * DIM + swz * 8;
    gB3[i] = b3e + (size_t)(n0 + r) * DIM + swz * 8;
  }
  char* dA  = (char*)sA  + tid * 16;
  char* dB1 = (char*)sB1 + tid * 16;
  char* dB3 = (char*)sB3 + tid * 16;

  f32x4 acc1[4][4], acc3[4][4];
#pragma unroll
  for (int m = 0; m < 4; ++m)
#pragma unroll
    for (int n = 0; n < 4; ++n) { acc1[m][n] = {0, 0, 0, 0}; acc3[m][n] = {0, 0, 0, 0}; }

  for (int kt = 0; kt < DIM / BK; ++kt) {
    const int koff = kt * BK;
#pragma unroll
    for (int i = 0; i < 4; ++i) {
      async_copy16(gA[i]  + koff, dA  + i * 4096);
      async_copy16(gB1[i] + koff, dB1 + i * 4096);
      async_copy16(gB3[i] + koff, dB3 + i * 4096);
    }
    __syncthreads();   // drains vmcnt(0) before ds_read
#pragma unroll
    for (int kk = 0; kk < 2; ++kk) {
      short8 af[4], b1f[4], b3f[4];
#pragma unroll
      for (int m = 0; m < 4; ++m) {
        int r = wrow + m * 16 + (lane & 15);
        int ch = (kk * 4 + (lane >> 4)) ^ (lane & 7);   // inverse swizzle (r&7 == lane&7)
        af[m] = *(const short8*)((const char*)sA + r * 128 + ch * 16);
      }
#pragma unroll
      for (int n = 0; n < 4; ++n) {
        int r = wcol + n * 16 + (lane & 15);
        int ch = (kk * 4 + (lane >> 4)) ^ (lane & 7);
        b1f[n] = *(const short8*)((const char*)sB1 + r * 128 + ch * 16);
        b3f[n] = *(const short8*)((const char*)sB3 + r * 128 + ch * 16);
      }
#pragma unroll
      for (int m = 0; m < 4; ++m)
#pragma unroll
        for (int n = 0; n < 4; ++n) {
          acc1[m][n] = __builtin_amdgcn_mfma_f32_16x16x32_bf16(af[m], b1f[n], acc1[m][n], 0, 0, 0);
          acc3[m][n] = __builtin_amdgcn_mfma_f32_16x16x32_bf16(af[m], b3f[n], acc3[m][n], 0, 0, 0);
        }
    }
    __syncthreads();
  }

  const int hb = offsets[e];
#pragma unroll
  for (int m = 0; m < 4; ++m) {
#pragma unroll
    for (int j = 0; j < 4; ++j) {
      int ridx = m0 + wrow + m * 16 + ((lane >> 4) << 2) + j;   // C/D: row=fq*4+j, col=fr
      if (ridx < cnt) {
        __hip_bfloat16* hr = h + (size_t)(hb + ridx) * FF + n0 + wcol + (lane & 15);
#pragma unroll
        for (int n = 0; n < 4; ++n) {
          float v1 = acc1[m][n][j], v3 = acc3[m][n][j];
          hr[n * 16] = __float2bfloat16(silu_f(v1) * v3);
        }
      }
    }
  }
}

// ---------------- expert down-proj: out[token] += w * (h @ w2) ----------------
__global__ __launch_bounds__(256, 2) void k_expert_down(
    const __hip_bfloat16* __restrict__ h,     // [2*NTOK][FF]
    const __hip_bfloat16* __restrict__ w2t,   // [E][DIM][FF]  (n-major)
    const int* __restrict__ slot_token, const float* __restrict__ slot_w,
    const int* __restrict__ counts, const int* __restrict__ offsets,
    float* __restrict__ out)                  // [NTOK][DIM], zeroed
{
  const int e = blockIdx.z;
  const int cnt = counts[e];
  const int m0 = blockIdx.y * BM;
  if (m0 >= cnt) return;
  const int n0 = blockIdx.x * BN;
  const int tid = threadIdx.x, lane = tid & 63, wave = tid >> 6;
  const int wrow = (wave >> 1) * 64, wcol = (wave & 1) * 64;

  __shared__ __hip_bfloat16 sA[BM * BK];
  __shared__ __hip_bfloat16 sB[BN * BK];

  const int srow = tid >> 3, scol = tid & 7;
  const int swz = scol ^ (srow & 7);

  const int hb = offsets[e];
  const __hip_bfloat16* b2e = w2t + (size_t)e * DIM * FF;

  const __hip_bfloat16 *gA[4], *gB[4];
#pragma unroll
  for (int i = 0; i < 4; ++i) {
    int r = i * 32 + srow;
    int idx = m0 + r;
    if (idx >= cnt) idx = 0;                  // clamp into valid h rows
    gA[i] = h   + (size_t)(hb + idx) * FF + swz * 8;   // h compact: no gather on A
    gB[i] = b2e + (size_t)(n0 + r) * FF + swz * 8;
  }
  char* dA = (char*)sA + tid * 16;
  char* dB = (char*)sB + tid * 16;

  f32x4 acc[4][4];
#pragma unroll
  for (int m = 0; m < 4; ++m)
#pragma unroll
    for (int n = 0; n < 4; ++n) acc[m][n] = {0, 0, 0, 0};

  for (int kt = 0; kt < FF / BK; ++kt) {
    const int koff = kt * BK;
#pragma unroll
    for (int i = 0; i < 4; ++i) {
      async_copy16(gA[i] + koff, dA + i * 4096);
      async_copy16(gB[i] + koff, dB + i * 4096);
    }
    __syncthreads();
#pragma unroll
    for (int kk = 0; kk < 2; ++kk) {
      short8 af[4], bf[4];
#pragma unroll
      for (int m = 0; m < 4; ++m) {
        int r = wrow + m * 16 + (lane & 15);
        int ch = (kk * 4 + (lane >> 4)) ^ (lane & 7);
        af[m] = *(const short8*)((const char*)sA + r * 128 + ch * 16);
      }
#pragma unroll
      for (int n = 0; n < 4; ++n) {
        int r = wcol + n * 16 + (lane & 15);
        int ch = (kk * 4 + (lane >> 4)) ^ (lane & 7);
        bf[n] = *(const short8*)((const char*)sB + r * 128 + ch * 16);
      }
#pragma unroll
      for (int m = 0; m < 4; ++m)
#pragma unroll
        for (int n = 0; n < 4; ++n)
          acc[m][n] = __builtin_amdgcn_mfma_f32_16x16x32_bf16(af[m], bf[n], acc[m][n], 0, 0, 0);
    }
    __syncthreads();
  }

  // Each output element receives exactly 2 expert contributions -> fire-and-forget
  // device-scope f32 atomics (~67MB traffic, est. 20-35us). Revisit if counters object.
#pragma unroll
  for (int m = 0; m < 4; ++m) {
#pragma unroll
    for (int j = 0; j < 4; ++j) {
      int ridx = m0 + wrow + m * 16 + ((lane >> 4) << 2) + j;
      if (ridx < cnt) {
        int   tok = slot_token[e * NTOK + ridx];
        float wgt = slot_w[e * NTOK + ridx];
        float* orow = out + (size_t)tok * DIM + n0 + wcol + (lane & 15);
#pragma unroll
        for (int n = 0; n < 4; ++n) atomicAdd(&orow[n * 16], wgt * acc[m][n][j]);
      }
    }
  }
}

// ---------------------------------------------------------------------------
extern "C" void kernel_launch(void* const* d_in, const int* in_sizes, int n_in,
                              void* d_out, int out_size, void* d_ws, size_t ws_size,
                              hipStream_t stream) {
  const float* x      = (const float*)d_in[0];
  const float* gate_w = (const float*)d_in[1];
  const float* w1     = (const float*)d_in[2];
  const float* w3     = (const float*)d_in[3];
  const float* w2     = (const float*)d_in[4];

  float* out    = (float*)d_out;                  // [NTOK][DIM]
  float* logits = out + (size_t)NTOK * DIM;       // [NTOK][NE]

  char* ws = (char*)d_ws;
  size_t cur = 0;
  auto take = [&](size_t bytes) {
    size_t r = cur;
    cur += (bytes + 255) & ~(size_t)255;
    return r;
  };
  // ws budget (~144.5 MB): slots 0.5MB + xb 16MB + w1t 32MB + w3t 32MB + hbuf 64MB.
  // w2t ALIASES w1t: its transpose is launched after k_expert_up (stream-serial,
  // w1t dead by then) - saves 32MB of workspace.
  int*   counts     = (int*)(ws + take(32));
  int*   offsets    = (int*)(ws + take(32));
  int*   slot_token = (int*)(ws + take((size_t)NE * NTOK * 4));
  float* slot_w     = (float*)(ws + take((size_t)NE * NTOK * 4));
  __hip_bfloat16* xb  = (__hip_bfloat16*)(ws + take((size_t)NTOK * DIM * 2));
  __hip_bfloat16* w1t = (__hip_bfloat16*)(ws + take((size_t)NE * DIM * FF * 2));
  __hip_bfloat16* w3t = (__hip_bfloat16*)(ws + take((size_t)NE * DIM * FF * 2));
  __hip_bfloat16* hbuf = (__hip_bfloat16*)(ws + take((size_t)2 * NTOK * FF * 2));
  __hip_bfloat16* w2t = w1t;                      // alias (see above)

  hipMemsetAsync(counts, 0, 64, stream);
  hipMemsetAsync(out, 0, (size_t)NTOK * DIM * sizeof(float), stream);

  k_convx<<<NTOK * DIM / 8 / 256, 256, 0, stream>>>(x, xb);
  k_tconv<<<dim3(FF / 32, DIM / 32, NE), 256, 0, stream>>>(w1, w1t, DIM, FF);
  k_tconv<<<dim3(FF / 32, DIM / 32, NE), 256, 0, stream>>>(w3, w3t, DIM, FF);
  k_router<<<NTOK / 4, 256, 0, stream>>>(x, gate_w, logits, slot_token, slot_w, counts);
  k_scan<<<1, 64, 0, stream>>>(counts, offsets);
  k_expert_up<<<dim3(FF / BN, NTOK / BM, NE), 256, 0, stream>>>(
      xb, w1t, w3t, slot_token, counts, offsets, hbuf);
  k_tconv<<<dim3(DIM / 32, FF / 32, NE), 256, 0, stream>>>(w2, w2t, FF, DIM);  // after up: w1t dead
  k_expert_down<<<dim3(DIM / BN, NTOK / BM, NE), 256, 0, stream>>>(
      hbuf, w2t, slot_token, slot_w, counts, offsets, out);
}

// Round 3
// 573.521 us; speedup vs baseline: 1.2781x; 1.2781x over previous
//
#include <hip/hip_runtime.h>
#include <hip/hip_bf16.h>

#define DEV __device__ __forceinline__

typedef __attribute__((ext_vector_type(8))) short short8;
typedef __attribute__((ext_vector_type(4))) float f32x4;

constexpr int NTOK = 8192;   // B*L
constexpr int DIM  = 1024;   // D
constexpr int FF   = 2048;   // F
constexpr int NE   = 8;      // experts
constexpr int BM = 128, BN = 128, BK = 64;

// ---------------- async global->LDS, 16B per lane ----------------
DEV void async_copy16(const void* g, void* l) {
  __builtin_amdgcn_global_load_lds(
      (const __attribute__((address_space(1))) unsigned int*)g,
      (__attribute__((address_space(3))) unsigned int*)l, 16, 0, 0);
}

DEV float silu_f(float v) { return v / (1.f + __expf(-v)); }

// ---------------- x fp32 -> bf16, 8 elems/thread ----------------
__global__ void k_convx(const float* __restrict__ x, __hip_bfloat16* __restrict__ xb) {
  size_t i = (size_t)blockIdx.x * blockDim.x + threadIdx.x;  // one per 8 elements
  const float4* s = (const float4*)x + i * 2;
  float4 a = s[0], b = s[1];
  __hip_bfloat16 tmp[8];
  tmp[0] = __float2bfloat16(a.x); tmp[1] = __float2bfloat16(a.y);
  tmp[2] = __float2bfloat16(a.z); tmp[3] = __float2bfloat16(a.w);
  tmp[4] = __float2bfloat16(b.x); tmp[5] = __float2bfloat16(b.y);
  tmp[6] = __float2bfloat16(b.z); tmp[7] = __float2bfloat16(b.w);
  *(short8*)(xb + i * 8) = *(const short8*)tmp;
}

// ---------- transpose-convert: src [R][C] fp32 -> dst [C][R] bf16, per expert z ----------
__global__ void k_tconv(const float* __restrict__ src, __hip_bfloat16* __restrict__ dst,
                        int R, int C) {
  const size_t esz = (size_t)R * C;
  src += esz * blockIdx.z;
  dst += esz * blockIdx.z;
  __shared__ float tile[32][33];            // +1 pad: conflict-free transpose
  const int t = threadIdx.x;
  const int r0 = blockIdx.y * 32, c0 = blockIdx.x * 32;
#pragma unroll
  for (int i = 0; i < 4; ++i) {
    int lr = i * 8 + (t >> 5), lc = t & 31;
    tile[lr][lc] = src[(size_t)(r0 + lr) * C + c0 + lc];
  }
  __syncthreads();
#pragma unroll
  for (int i = 0; i < 4; ++i) {
    int cc = i * 8 + (t >> 5), rr = t & 31;
    dst[(size_t)(c0 + cc) * R + r0 + rr] = __float2bfloat16(tile[rr][cc]);
  }
}

// ---------------- router: fp32 logits, top-2, softmax. NO atomics. ----------------
// Round-2 lesson: 16384 device-atomics on one cache line serialized at ~12ns each
// (193us, VALUBusy 1.6%). Placement moved to k_place (block-level histogram).
__global__ void k_router(const float* __restrict__ x, const float* __restrict__ gw,
                         float* __restrict__ logits, int* __restrict__ tok_i,
                         float2* __restrict__ tok_w) {
  const int wave = threadIdx.x >> 6, lane = threadIdx.x & 63;
  const int tok = blockIdx.x * 4 + wave;
  float acc[NE];
#pragma unroll
  for (int e = 0; e < NE; ++e) acc[e] = 0.f;
  const float4* xr = (const float4*)(x + (size_t)tok * DIM);
#pragma unroll
  for (int i = 0; i < DIM / 256; ++i) {     // float4 x loads: 4 iters
    int d4 = i * 64 + lane;                 // index in float4 units
    float4 xv = xr[d4];
    const float4* g = (const float4*)(gw + (size_t)d4 * 4 * NE);
    float xs[4] = {xv.x, xv.y, xv.z, xv.w};
#pragma unroll
    for (int r = 0; r < 4; ++r) {           // 4 gw rows per lane (L1/L2-resident, 32KB total)
      float4 ga = g[r * 2], gb = g[r * 2 + 1];
      acc[0] += xs[r] * ga.x; acc[1] += xs[r] * ga.y;
      acc[2] += xs[r] * ga.z; acc[3] += xs[r] * ga.w;
      acc[4] += xs[r] * gb.x; acc[5] += xs[r] * gb.y;
      acc[6] += xs[r] * gb.z; acc[7] += xs[r] * gb.w;
    }
  }
#pragma unroll
  for (int e = 0; e < NE; ++e) {
#pragma unroll
    for (int off = 32; off; off >>= 1) acc[e] += __shfl_xor(acc[e], off);
  }
  if (lane == 0) {
#pragma unroll
    for (int e = 0; e < NE; ++e) logits[(size_t)tok * NE + e] = acc[e];
    // top-2, JAX tie-break (lowest index first) via strict >
    int i0 = 0; float m0 = acc[0];
#pragma unroll
    for (int e = 1; e < NE; ++e) if (acc[e] > m0) { m0 = acc[e]; i0 = e; }
    int i1 = -1; float m1 = -3.4e38f;
#pragma unroll
    for (int e = 0; e < NE; ++e) if (e != i0 && acc[e] > m1) { m1 = acc[e]; i1 = e; }
    float p  = __expf(m1 - m0);           // <= 1
    float wA = 1.f / (1.f + p);           // softmax over the 2 selected logits
    float wB = p * wA;
    tok_i[tok] = i0 | (i1 << 4);
    tok_w[tok] = make_float2(wA, wB);
  }
}

// ---------------- placement: LDS histogram -> 8 global atomics per block ----------------
__global__ void k_place(const int* __restrict__ tok_i, const float2* __restrict__ tok_w,
                        int* __restrict__ slot_token, float* __restrict__ slot_w,
                        int* __restrict__ counts) {
  __shared__ int lcnt[NE], lbase[NE];
  const int t = threadIdx.x;
  const int tok = blockIdx.x * 256 + t;
  if (t < NE) lcnt[t] = 0;
  __syncthreads();
  int pk = tok_i[tok];
  int e0 = pk & 15, e1 = pk >> 4;
  float2 w = tok_w[tok];
  int p0 = atomicAdd(&lcnt[e0], 1);        // LDS atomics: cheap
  int p1 = atomicAdd(&lcnt[e1], 1);
  __syncthreads();
  if (t < NE) lbase[t] = atomicAdd(&counts[t], lcnt[t]);   // 8 global atomics/block
  __syncthreads();
  int s0 = e0 * NTOK + lbase[e0] + p0;
  slot_token[s0] = tok; slot_w[s0] = w.x;
  int s1 = e1 * NTOK + lbase[e1] + p1;
  slot_token[s1] = tok; slot_w[s1] = w.y;
}

__global__ void k_scan(const int* __restrict__ counts, int* __restrict__ offsets) {
  if (threadIdx.x == 0) {
    int s = 0;
    for (int e = 0; e < NE; ++e) { offsets[e] = s; s += counts[e]; }
  }
}

// ---------------- expert up-proj: h = silu(x@w1) * (x@w3), gathered rows ----------------
// m97 structure: single-buffer LDS, global_load_lds w16, XOR-swizzled (T2),
// 128x128 tile, 4 waves, 16x16x32 bf16 MFMA. Two B operands share the A tile.
__global__ __launch_bounds__(256, 2) void k_expert_up(
    const __hip_bfloat16* __restrict__ xb,    // [NTOK][DIM]
    const __hip_bfloat16* __restrict__ w1t,   // [E][FF][DIM]  (n-major)
    const __hip_bfloat16* __restrict__ w3t,   // [E][FF][DIM]
    const int* __restrict__ slot_token, const int* __restrict__ counts,
    const int* __restrict__ offsets,
    __hip_bfloat16* __restrict__ h)           // [2*NTOK][FF] compact
{
  const int e  = blockIdx.z;
  const int cnt = counts[e];
  const int m0 = blockIdx.y * BM;
  if (m0 >= cnt) return;
  const int n0 = blockIdx.x * BN;
  const int tid = threadIdx.x, lane = tid & 63, wave = tid >> 6;
  const int wrow = (wave >> 1) * 64, wcol = (wave & 1) * 64;

  __shared__ __hip_bfloat16 sA[BM * BK];
  __shared__ __hip_bfloat16 sB1[BN * BK];
  __shared__ __hip_bfloat16 sB3[BN * BK];

  const int srow = tid >> 3, scol = tid & 7;
  const int swz = scol ^ (srow & 7);          // T2: source-side pre-swizzle (m173)

  const int* stok = slot_token + e * NTOK;
  const __hip_bfloat16* b1e = w1t + (size_t)e * FF * DIM;
  const __hip_bfloat16* b3e = w3t + (size_t)e * FF * DIM;

  const __hip_bfloat16 *gA[4], *gB1[4], *gB3[4];
#pragma unroll
  for (int i = 0; i < 4; ++i) {
    int r = i * 32 + srow;
    int idx = m0 + r;
    int tokv = (idx < cnt) ? stok[idx] : 0;   // clamp padded rows to a valid token
    gA[i]  = xb  + (size_t)tokv * DIM + swz * 8;
    gB1[i] = b1e + (size_t)(n0 + r) * DIM + swz * 8;
    gB3[i] = b3e + (size_t)(n0 + r) * DIM + swz * 8;
  }
  char* dA  = (char*)sA  + tid * 16;
  char* dB1 = (char*)sB1 + tid * 16;
  char* dB3 = (char*)sB3 + tid * 16;

  f32x4 acc1[4][4], acc3[4][4];
#pragma unroll
  for (int m = 0; m < 4; ++m)
#pragma unroll
    for (int n = 0; n < 4; ++n) { acc1[m][n] = {0, 0, 0, 0}; acc3[m][n] = {0, 0, 0, 0}; }

  for (int kt = 0; kt < DIM / BK; ++kt) {
    const int koff = kt * BK;
#pragma unroll
    for (int i = 0; i < 4; ++i) {
      async_copy16(gA[i]  + koff, dA  + i * 4096);
      async_copy16(gB1[i] + koff, dB1 + i * 4096);
      async_copy16(gB3[i] + koff, dB3 + i * 4096);
    }
    __syncthreads();   // drains vmcnt(0) before ds_read
#pragma unroll
    for (int kk = 0; kk < 2; ++kk) {
      short8 af[4], b1f[4], b3f[4];
#pragma unroll
      for (int m = 0; m < 4; ++m) {
        int r = wrow + m * 16 + (lane & 15);
        int ch = (kk * 4 + (lane >> 4)) ^ (lane & 7);   // inverse swizzle (r&7 == lane&7)
        af[m] = *(const short8*)((const char*)sA + r * 128 + ch * 16);
      }
#pragma unroll
      for (int n = 0; n < 4; ++n) {
        int r = wcol + n * 16 + (lane & 15);
        int ch = (kk * 4 + (lane >> 4)) ^ (lane & 7);
        b1f[n] = *(const short8*)((const char*)sB1 + r * 128 + ch * 16);
        b3f[n] = *(const short8*)((const char*)sB3 + r * 128 + ch * 16);
      }
#pragma unroll
      for (int m = 0; m < 4; ++m)
#pragma unroll
        for (int n = 0; n < 4; ++n) {
          acc1[m][n] = __builtin_amdgcn_mfma_f32_16x16x32_bf16(af[m], b1f[n], acc1[m][n], 0, 0, 0);
          acc3[m][n] = __builtin_amdgcn_mfma_f32_16x16x32_bf16(af[m], b3f[n], acc3[m][n], 0, 0, 0);
        }
    }
    __syncthreads();
  }

  const int hb = offsets[e];
#pragma unroll
  for (int m = 0; m < 4; ++m) {
#pragma unroll
    for (int j = 0; j < 4; ++j) {
      int ridx = m0 + wrow + m * 16 + ((lane >> 4) << 2) + j;   // C/D: row=fq*4+j, col=fr
      if (ridx < cnt) {
        __hip_bfloat16* hr = h + (size_t)(hb + ridx) * FF + n0 + wcol + (lane & 15);
#pragma unroll
        for (int n = 0; n < 4; ++n) {
          float v1 = acc1[m][n][j], v3 = acc3[m][n][j];
          hr[n * 16] = __float2bfloat16(silu_f(v1) * v3);
        }
      }
    }
  }
}

// ---------------- expert down-proj: out[token] += w * (h @ w2) ----------------
__global__ __launch_bounds__(256, 2) void k_expert_down(
    const __hip_bfloat16* __restrict__ h,     // [2*NTOK][FF]
    const __hip_bfloat16* __restrict__ w2t,   // [E][DIM][FF]  (n-major)
    const int* __restrict__ slot_token, const float* __restrict__ slot_w,
    const int* __restrict__ counts, const int* __restrict__ offsets,
    float* __restrict__ out)                  // [NTOK][DIM], zeroed
{
  const int e = blockIdx.z;
  const int cnt = counts[e];
  const int m0 = blockIdx.y * BM;
  if (m0 >= cnt) return;
  const int n0 = blockIdx.x * BN;
  const int tid = threadIdx.x, lane = tid & 63, wave = tid >> 6;
  const int wrow = (wave >> 1) * 64, wcol = (wave & 1) * 64;

  __shared__ __hip_bfloat16 sA[BM * BK];
  __shared__ __hip_bfloat16 sB[BN * BK];

  const int srow = tid >> 3, scol = tid & 7;
  const int swz = scol ^ (srow & 7);

  const int hb = offsets[e];
  const __hip_bfloat16* b2e = w2t + (size_t)e * DIM * FF;

  const __hip_bfloat16 *gA[4], *gB[4];
#pragma unroll
  for (int i = 0; i < 4; ++i) {
    int r = i * 32 + srow;
    int idx = m0 + r;
    if (idx >= cnt) idx = 0;                  // clamp into valid h rows
    gA[i] = h   + (size_t)(hb + idx) * FF + swz * 8;   // h compact: no gather on A
    gB[i] = b2e + (size_t)(n0 + r) * FF + swz * 8;
  }
  char* dA = (char*)sA + tid * 16;
  char* dB = (char*)sB + tid * 16;

  f32x4 acc[4][4];
#pragma unroll
  for (int m = 0; m < 4; ++m)
#pragma unroll
    for (int n = 0; n < 4; ++n) acc[m][n] = {0, 0, 0, 0};

  for (int kt = 0; kt < FF / BK; ++kt) {
    const int koff = kt * BK;
#pragma unroll
    for (int i = 0; i < 4; ++i) {
      async_copy16(gA[i] + koff, dA + i * 4096);
      async_copy16(gB[i] + koff, dB + i * 4096);
    }
    __syncthreads();
#pragma unroll
    for (int kk = 0; kk < 2; ++kk) {
      short8 af[4], bf[4];
#pragma unroll
      for (int m = 0; m < 4; ++m) {
        int r = wrow + m * 16 + (lane & 15);
        int ch = (kk * 4 + (lane >> 4)) ^ (lane & 7);
        af[m] = *(const short8*)((const char*)sA + r * 128 + ch * 16);
      }
#pragma unroll
      for (int n = 0; n < 4; ++n) {
        int r = wcol + n * 16 + (lane & 15);
        int ch = (kk * 4 + (lane >> 4)) ^ (lane & 7);
        bf[n] = *(const short8*)((const char*)sB + r * 128 + ch * 16);
      }
#pragma unroll
      for (int m = 0; m < 4; ++m)
#pragma unroll
        for (int n = 0; n < 4; ++n)
          acc[m][n] = __builtin_amdgcn_mfma_f32_16x16x32_bf16(af[m], bf[n], acc[m][n], 0, 0, 0);
    }
    __syncthreads();
  }

  // Each output element receives exactly 2 expert contributions -> fire-and-forget
  // device-scope f32 atomics (~67MB traffic). Revisit if counters object.
#pragma unroll
  for (int m = 0; m < 4; ++m) {
#pragma unroll
    for (int j = 0; j < 4; ++j) {
      int ridx = m0 + wrow + m * 16 + ((lane >> 4) << 2) + j;
      if (ridx < cnt) {
        int   tok = slot_token[e * NTOK + ridx];
        float wgt = slot_w[e * NTOK + ridx];
        float* orow = out + (size_t)tok * DIM + n0 + wcol + (lane & 15);
#pragma unroll
        for (int n = 0; n < 4; ++n) atomicAdd(&orow[n * 16], wgt * acc[m][n][j]);
      }
    }
  }
}

// ---------------------------------------------------------------------------
extern "C" void kernel_launch(void* const* d_in, const int* in_sizes, int n_in,
                              void* d_out, int out_size, void* d_ws, size_t ws_size,
                              hipStream_t stream) {
  const float* x      = (const float*)d_in[0];
  const float* gate_w = (const float*)d_in[1];
  const float* w1     = (const float*)d_in[2];
  const float* w3     = (const float*)d_in[3];
  const float* w2     = (const float*)d_in[4];

  float* out    = (float*)d_out;                  // [NTOK][DIM]
  float* logits = out + (size_t)NTOK * DIM;       // [NTOK][NE]

  char* ws = (char*)d_ws;
  size_t cur = 0;
  auto take = [&](size_t bytes) {
    size_t r = cur;
    cur += (bytes + 255) & ~(size_t)255;
    return r;
  };
  // ws budget (~144.6 MB): slots/topk ~0.6MB + xb 16MB + w1t 32MB + w3t 32MB + hbuf 64MB.
  // w2t ALIASES w1t: its transpose runs after k_expert_up (stream-serial, w1t dead).
  int*    counts     = (int*)(ws + take(32));
  int*    offsets    = (int*)(ws + take(32));
  int*    slot_token = (int*)(ws + take((size_t)NE * NTOK * 4));
  float*  slot_w     = (float*)(ws + take((size_t)NE * NTOK * 4));
  int*    tok_i      = (int*)(ws + take((size_t)NTOK * 4));
  float2* tok_w      = (float2*)(ws + take((size_t)NTOK * 8));
  __hip_bfloat16* xb  = (__hip_bfloat16*)(ws + take((size_t)NTOK * DIM * 2));
  __hip_bfloat16* w1t = (__hip_bfloat16*)(ws + take((size_t)NE * DIM * FF * 2));
  __hip_bfloat16* w3t = (__hip_bfloat16*)(ws + take((size_t)NE * DIM * FF * 2));
  __hip_bfloat16* hbuf = (__hip_bfloat16*)(ws + take((size_t)2 * NTOK * FF * 2));
  __hip_bfloat16* w2t = w1t;                      // alias (see above)

  hipMemsetAsync(counts, 0, 64, stream);
  hipMemsetAsync(out, 0, (size_t)NTOK * DIM * sizeof(float), stream);

  k_convx<<<NTOK * DIM / 8 / 256, 256, 0, stream>>>(x, xb);
  k_tconv<<<dim3(FF / 32, DIM / 32, NE), 256, 0, stream>>>(w1, w1t, DIM, FF);
  k_tconv<<<dim3(FF / 32, DIM / 32, NE), 256, 0, stream>>>(w3, w3t, DIM, FF);
  k_router<<<NTOK / 4, 256, 0, stream>>>(x, gate_w, logits, tok_i, tok_w);
  k_place<<<NTOK / 256, 256, 0, stream>>>(tok_i, tok_w, slot_token, slot_w, counts);
  k_scan<<<1, 64, 0, stream>>>(counts, offsets);
  k_expert_up<<<dim3(FF / BN, NTOK / BM, NE), 256, 0, stream>>>(
      xb, w1t, w3t, slot_token, counts, offsets, hbuf);
  k_tconv<<<dim3(DIM / 32, FF / 32, NE), 256, 0, stream>>>(w2, w2t, FF, DIM);  // after up: w1t dead
  k_expert_down<<<dim3(DIM / BN, NTOK / BM, NE), 256, 0, stream>>>(
      hbuf, w2t, slot_token, slot_w, counts, offsets, out);
}

// Round 4
// 546.150 us; speedup vs baseline: 1.3422x; 1.0501x over previous
//
#include <hip/hip_runtime.h>
#include <hip/hip_bf16.h>

#define DEV __device__ __forceinline__

typedef __attribute__((ext_vector_type(8))) short short8;
typedef __attribute__((ext_vector_type(4))) short short4v;
typedef __attribute__((ext_vector_type(4))) float f32x4;

constexpr int NTOK = 8192;   // B*L
constexpr int DIM  = 1024;   // D
constexpr int FF   = 2048;   // F
constexpr int NE   = 8;      // experts
constexpr int BM = 128, BN = 128, BK = 64;

// ---------------- async global->LDS, 16B per lane ----------------
DEV void async_copy16(const void* g, void* l) {
  __builtin_amdgcn_global_load_lds(
      (const __attribute__((address_space(1))) unsigned int*)g,
      (__attribute__((address_space(3))) unsigned int*)l, 16, 0, 0);
}

DEV float silu_f(float v) { return v / (1.f + __expf(-v)); }

// ---------- transpose-convert v2: src [R][C] fp32 -> dst [C][R] bf16, per expert z ----
// 64(R) x 32(C) tile; reads float4/lane, writes short8 (16B)/lane.
// Round-3 lesson: v1 wrote 2B/lane (64B per half-wave) - ~2x write inefficiency.
__global__ void k_tconv(const float* __restrict__ src, __hip_bfloat16* __restrict__ dst,
                        int R, int C) {
  const size_t esz = (size_t)R * C;
  src += esz * blockIdx.z;
  dst += esz * blockIdx.z;
  __shared__ float tile[64][33];
  const int t = threadIdx.x;                 // 256
  const int r0 = blockIdx.y * 64, c0 = blockIdx.x * 32;
  // read: thread t -> row r = t>>2, cols (t&3)*8 .. +7  (two float4)
  {
    int r = t >> 2, cb = (t & 3) * 8;
    const float4* s = (const float4*)(src + (size_t)(r0 + r) * C + c0 + cb);
    float4 a = s[0], b = s[1];
    tile[r][cb + 0] = a.x; tile[r][cb + 1] = a.y; tile[r][cb + 2] = a.z; tile[r][cb + 3] = a.w;
    tile[r][cb + 4] = b.x; tile[r][cb + 5] = b.y; tile[r][cb + 6] = b.z; tile[r][cb + 7] = b.w;
  }
  __syncthreads();
  // write: thread t -> out-row c = t>>3, rows (t&7)*8 .. +7 -> one short8 store
  {
    int c = t >> 3, rb = (t & 7) * 8;
    __hip_bfloat16 tmp[8];
#pragma unroll
    for (int k = 0; k < 8; ++k) tmp[k] = __float2bfloat16(tile[rb + k][c]);
    *(short8*)(dst + (size_t)(c0 + c) * R + r0 + rb) = *(const short8*)tmp;
  }
}

// ---------------- router: fp32 logits, top-2, softmax; also emits xb (bf16 x) ----------
// fp32 math on purpose: top-k is discrete, bf16 logits could flip expert choice.
__global__ void k_router(const float* __restrict__ x, const float* __restrict__ gw,
                         float* __restrict__ logits, int* __restrict__ tok_i,
                         float2* __restrict__ tok_w, __hip_bfloat16* __restrict__ xb) {
  const int wave = threadIdx.x >> 6, lane = threadIdx.x & 63;
  const int tok = blockIdx.x * 4 + wave;
  float acc[NE];
#pragma unroll
  for (int e = 0; e < NE; ++e) acc[e] = 0.f;
  const float4* xr = (const float4*)(x + (size_t)tok * DIM);
#pragma unroll
  for (int i = 0; i < DIM / 256; ++i) {     // 4 iters, float4/lane
    int d4 = i * 64 + lane;
    float4 xv = xr[d4];
    // fused x -> bf16 (replaces k_convx; saves a 32MB re-read)
    __hip_bfloat16 xc[4] = {__float2bfloat16(xv.x), __float2bfloat16(xv.y),
                            __float2bfloat16(xv.z), __float2bfloat16(xv.w)};
    *(short4v*)(xb + (size_t)tok * DIM + d4 * 4) = *(const short4v*)xc;
    const float4* g = (const float4*)(gw + (size_t)d4 * 4 * NE);
    float xs[4] = {xv.x, xv.y, xv.z, xv.w};
#pragma unroll
    for (int r = 0; r < 4; ++r) {           // gw is 32KB -> L1/L2-resident
      float4 ga = g[r * 2], gb = g[r * 2 + 1];
      acc[0] += xs[r] * ga.x; acc[1] += xs[r] * ga.y;
      acc[2] += xs[r] * ga.z; acc[3] += xs[r] * ga.w;
      acc[4] += xs[r] * gb.x; acc[5] += xs[r] * gb.y;
      acc[6] += xs[r] * gb.z; acc[7] += xs[r] * gb.w;
    }
  }
#pragma unroll
  for (int e = 0; e < NE; ++e) {
#pragma unroll
    for (int off = 32; off; off >>= 1) acc[e] += __shfl_xor(acc[e], off);
  }
  if (lane == 0) {
#pragma unroll
    for (int e = 0; e < NE; ++e) logits[(size_t)tok * NE + e] = acc[e];
    // top-2, JAX tie-break (lowest index first) via strict >
    int i0 = 0; float m0 = acc[0];
#pragma unroll
    for (int e = 1; e < NE; ++e) if (acc[e] > m0) { m0 = acc[e]; i0 = e; }
    int i1 = -1; float m1 = -3.4e38f;
#pragma unroll
    for (int e = 0; e < NE; ++e) if (e != i0 && acc[e] > m1) { m1 = acc[e]; i1 = e; }
    float p  = __expf(m1 - m0);           // <= 1
    float wA = 1.f / (1.f + p);           // softmax over the 2 selected logits
    float wB = p * wA;
    tok_i[tok] = i0 | (i1 << 4);
    tok_w[tok] = make_float2(wA, wB);
  }
}

// ---------------- placement: LDS histogram -> 8 global atomics per block --------------
// Also records the inverse map tok -> (expert-local slot) for the combine kernel.
__global__ void k_place(const int* __restrict__ tok_i, int* __restrict__ slot_token,
                        int* __restrict__ counts, int2* __restrict__ inv) {
  __shared__ int lcnt[NE], lbase[NE];
  const int t = threadIdx.x;
  const int tok = blockIdx.x * 256 + t;
  if (t < NE) lcnt[t] = 0;
  __syncthreads();
  int pk = tok_i[tok];
  int e0 = pk & 15, e1 = pk >> 4;
  int p0 = atomicAdd(&lcnt[e0], 1);        // LDS atomics: cheap
  int p1 = atomicAdd(&lcnt[e1], 1);
  __syncthreads();
  if (t < NE) lbase[t] = atomicAdd(&counts[t], lcnt[t]);   // 8 global atomics/block
  __syncthreads();
  int g0 = lbase[e0] + p0, g1 = lbase[e1] + p1;
  slot_token[e0 * NTOK + g0] = tok;
  slot_token[e1 * NTOK + g1] = tok;
  inv[tok] = make_int2(e0 * NTOK + g0, e1 * NTOK + g1);
}

__global__ void k_scan(const int* __restrict__ counts, int* __restrict__ offsets) {
  if (threadIdx.x == 0) {
    int s = 0;
    for (int e = 0; e < NE; ++e) { offsets[e] = s; s += counts[e]; }
  }
}

// ---------------- expert up-proj: h = silu(x@w1) * (x@w3), gathered rows ----------------
// m97 structure: single-buffer LDS, global_load_lds w16, XOR-swizzled (T2),
// 128x128 tile, 4 waves, 16x16x32 bf16 MFMA. Two B operands share the A tile.
// MfmaUtil 36% measured (r3) == the m97 structural ceiling; 8-phase port is next.
__global__ __launch_bounds__(256, 2) void k_expert_up(
    const __hip_bfloat16* __restrict__ xb,    // [NTOK][DIM]
    const __hip_bfloat16* __restrict__ w1t,   // [E][FF][DIM]  (n-major)
    const __hip_bfloat16* __restrict__ w3t,   // [E][FF][DIM]
    const int* __restrict__ slot_token, const int* __restrict__ counts,
    const int* __restrict__ offsets,
    __hip_bfloat16* __restrict__ h)           // [2*NTOK][FF] compact
{
  const int e  = blockIdx.z;
  const int cnt = counts[e];
  const int m0 = blockIdx.y * BM;
  if (m0 >= cnt) return;
  const int n0 = blockIdx.x * BN;
  const int tid = threadIdx.x, lane = tid & 63, wave = tid >> 6;
  const int wrow = (wave >> 1) * 64, wcol = (wave & 1) * 64;

  __shared__ __hip_bfloat16 sA[BM * BK];
  __shared__ __hip_bfloat16 sB1[BN * BK];
  __shared__ __hip_bfloat16 sB3[BN * BK];

  const int srow = tid >> 3, scol = tid & 7;
  const int swz = scol ^ (srow & 7);          // T2: source-side pre-swizzle (m173)

  const int* stok = slot_token + e * NTOK;
  const __hip_bfloat16* b1e = w1t + (size_t)e * FF * DIM;
  const __hip_bfloat16* b3e = w3t + (size_t)e * FF * DIM;

  const __hip_bfloat16 *gA[4], *gB1[4], *gB3[4];
#pragma unroll
  for (int i = 0; i < 4; ++i) {
    int r = i * 32 + srow;
    int idx = m0 + r;
    int tokv = (idx < cnt) ? stok[idx] : 0;   // clamp padded rows to a valid token
    gA[i]  = xb  + (size_t)tokv * DIM + swz * 8;
    gB1[i] = b1e + (size_t)(n0 + r) * DIM + swz * 8;
    gB3[i] = b3e + (size_t)(n0 + r) * DIM + swz * 8;
  }
  char* dA  = (char*)sA  + tid * 16;
  char* dB1 = (char*)sB1 + tid * 16;
  char* dB3 = (char*)sB3 + tid * 16;

  f32x4 acc1[4][4], acc3[4][4];
#pragma unroll
  for (int m = 0; m < 4; ++m)
#pragma unroll
    for (int n = 0; n < 4; ++n) { acc1[m][n] = {0, 0, 0, 0}; acc3[m][n] = {0, 0, 0, 0}; }

  for (int kt = 0; kt < DIM / BK; ++kt) {
    const int koff = kt * BK;
#pragma unroll
    for (int i = 0; i < 4; ++i) {
      async_copy16(gA[i]  + koff, dA  + i * 4096);
      async_copy16(gB1[i] + koff, dB1 + i * 4096);
      async_copy16(gB3[i] + koff, dB3 + i * 4096);
    }
    __syncthreads();   // drains vmcnt(0) before ds_read
#pragma unroll
    for (int kk = 0; kk < 2; ++kk) {
      short8 af[4], b1f[4], b3f[4];
#pragma unroll
      for (int m = 0; m < 4; ++m) {
        int r = wrow + m * 16 + (lane & 15);
        int ch = (kk * 4 + (lane >> 4)) ^ (lane & 7);   // inverse swizzle (r&7 == lane&7)
        af[m] = *(const short8*)((const char*)sA + r * 128 + ch * 16);
      }
#pragma unroll
      for (int n = 0; n < 4; ++n) {
        int r = wcol + n * 16 + (lane & 15);
        int ch = (kk * 4 + (lane >> 4)) ^ (lane & 7);
        b1f[n] = *(const short8*)((const char*)sB1 + r * 128 + ch * 16);
        b3f[n] = *(const short8*)((const char*)sB3 + r * 128 + ch * 16);
      }
#pragma unroll
      for (int m = 0; m < 4; ++m)
#pragma unroll
        for (int n = 0; n < 4; ++n) {
          acc1[m][n] = __builtin_amdgcn_mfma_f32_16x16x32_bf16(af[m], b1f[n], acc1[m][n], 0, 0, 0);
          acc3[m][n] = __builtin_amdgcn_mfma_f32_16x16x32_bf16(af[m], b3f[n], acc3[m][n], 0, 0, 0);
        }
    }
    __syncthreads();
  }

  const int hb = offsets[e];
#pragma unroll
  for (int m = 0; m < 4; ++m) {
#pragma unroll
    for (int j = 0; j < 4; ++j) {
      int ridx = m0 + wrow + m * 16 + ((lane >> 4) << 2) + j;   // C/D: row=fq*4+j, col=fr
      if (ridx < cnt) {
        __hip_bfloat16* hr = h + (size_t)(hb + ridx) * FF + n0 + wcol + (lane & 15);
#pragma unroll
        for (int n = 0; n < 4; ++n) {
          float v1 = acc1[m][n][j], v3 = acc3[m][n][j];
          hr[n * 16] = __float2bfloat16(silu_f(v1) * v3);
        }
      }
    }
  }
}

// ---------------- expert down-proj: stage[slot] = h @ w2 (NO atomics) ----------------
// Round-3 lesson candidate: 16.7M scattered device atomics were the suspected ~100us.
// Now: plain fp32 writes to compact slot-staging; k_combine does the weighted sum.
__global__ __launch_bounds__(256, 2) void k_expert_down(
    const __hip_bfloat16* __restrict__ h,     // [2*NTOK][FF]
    const __hip_bfloat16* __restrict__ w2t,   // [E][DIM][FF]  (n-major)
    const int* __restrict__ counts, const int* __restrict__ offsets,
    float* __restrict__ stage)                // [2*NTOK][DIM] compact
{
  const int e = blockIdx.z;
  const int cnt = counts[e];
  const int m0 = blockIdx.y * BM;
  if (m0 >= cnt) return;
  const int n0 = blockIdx.x * BN;
  const int tid = threadIdx.x, lane = tid & 63, wave = tid >> 6;
  const int wrow = (wave >> 1) * 64, wcol = (wave & 1) * 64;

  __shared__ __hip_bfloat16 sA[BM * BK];
  __shared__ __hip_bfloat16 sB[BN * BK];

  const int srow = tid >> 3, scol = tid & 7;
  const int swz = scol ^ (srow & 7);

  const int hb = offsets[e];
  const __hip_bfloat16* b2e = w2t + (size_t)e * DIM * FF;

  const __hip_bfloat16 *gA[4], *gB[4];
#pragma unroll
  for (int i = 0; i < 4; ++i) {
    int r = i * 32 + srow;
    int idx = m0 + r;
    if (idx >= cnt) idx = 0;                  // clamp into valid h rows
    gA[i] = h   + (size_t)(hb + idx) * FF + swz * 8;   // h compact: no gather on A
    gB[i] = b2e + (size_t)(n0 + r) * FF + swz * 8;
  }
  char* dA = (char*)sA + tid * 16;
  char* dB = (char*)sB + tid * 16;

  f32x4 acc[4][4];
#pragma unroll
  for (int m = 0; m < 4; ++m)
#pragma unroll
    for (int n = 0; n < 4; ++n) acc[m][n] = {0, 0, 0, 0};

  for (int kt = 0; kt < FF / BK; ++kt) {
    const int koff = kt * BK;
#pragma unroll
    for (int i = 0; i < 4; ++i) {
      async_copy16(gA[i] + koff, dA + i * 4096);
      async_copy16(gB[i] + koff, dB + i * 4096);
    }
    __syncthreads();
#pragma unroll
    for (int kk = 0; kk < 2; ++kk) {
      short8 af[4], bf[4];
#pragma unroll
      for (int m = 0; m < 4; ++m) {
        int r = wrow + m * 16 + (lane & 15);
        int ch = (kk * 4 + (lane >> 4)) ^ (lane & 7);
        af[m] = *(const short8*)((const char*)sA + r * 128 + ch * 16);
      }
#pragma unroll
      for (int n = 0; n < 4; ++n) {
        int r = wcol + n * 16 + (lane & 15);
        int ch = (kk * 4 + (lane >> 4)) ^ (lane & 7);
        bf[n] = *(const short8*)((const char*)sB + r * 128 + ch * 16);
      }
#pragma unroll
      for (int m = 0; m < 4; ++m)
#pragma unroll
        for (int n = 0; n < 4; ++n)
          acc[m][n] = __builtin_amdgcn_mfma_f32_16x16x32_bf16(af[m], bf[n], acc[m][n], 0, 0, 0);
    }
    __syncthreads();
  }

#pragma unroll
  for (int m = 0; m < 4; ++m) {
#pragma unroll
    for (int j = 0; j < 4; ++j) {
      int ridx = m0 + wrow + m * 16 + ((lane >> 4) << 2) + j;
      if (ridx < cnt) {
        float* sr = stage + (size_t)(hb + ridx) * DIM + n0 + wcol + (lane & 15);
#pragma unroll
        for (int n = 0; n < 4; ++n) sr[n * 16] = acc[m][n][j];   // plain coalesced f32
      }
    }
  }
}

// ---------------- combine: out[tok] = w0*stage[s0] + w1*stage[s1] ----------------
__global__ void k_combine(const float* __restrict__ stage, const int2* __restrict__ inv,
                          const float2* __restrict__ tok_w, const int* __restrict__ offsets,
                          float* __restrict__ out) {
  const int tok = blockIdx.x;
  int2 s = inv[tok];
  float2 w = tok_w[tok];
  int r0 = offsets[s.x >> 13] + (s.x & (NTOK - 1));
  int r1 = offsets[s.y >> 13] + (s.y & (NTOK - 1));
  const float4* a = (const float4*)(stage + (size_t)r0 * DIM);
  const float4* b = (const float4*)(stage + (size_t)r1 * DIM);
  float4* o = (float4*)(out + (size_t)tok * DIM);
  int c = threadIdx.x;                     // 256 threads x float4 = 1024 cols
  float4 va = a[c], vb = b[c];
  o[c] = make_float4(w.x * va.x + w.y * vb.x, w.x * va.y + w.y * vb.y,
                     w.x * va.z + w.y * vb.z, w.x * va.w + w.y * vb.w);
}

// ---------------------------------------------------------------------------
extern "C" void kernel_launch(void* const* d_in, const int* in_sizes, int n_in,
                              void* d_out, int out_size, void* d_ws, size_t ws_size,
                              hipStream_t stream) {
  const float* x      = (const float*)d_in[0];
  const float* gate_w = (const float*)d_in[1];
  const float* w1     = (const float*)d_in[2];
  const float* w3     = (const float*)d_in[3];
  const float* w2     = (const float*)d_in[4];

  float* out    = (float*)d_out;                  // [NTOK][DIM]
  float* logits = out + (size_t)NTOK * DIM;       // [NTOK][NE]

  char* ws = (char*)d_ws;
  size_t cur = 0;
  auto take = [&](size_t bytes) {
    size_t r = cur;
    cur += (bytes + 255) & ~(size_t)255;
    return r;
  };
  // ws budget ~168MB. Layout (lifetime-ordered for aliasing):
  //   small | w1t 33.6 | xb 16.8 | w3t 33.6 | pad 16.8 | hbuf 67.1
  // w2t ALIASES w1t (its tconv runs after k_expert_up; w1t dead then).
  // stage (fp32, 67.1MB) ALIASES xb+w3t+pad (all dead when k_expert_down writes it).
  int*    counts     = (int*)(ws + take(32));
  int*    offsets    = (int*)(ws + take(32));
  int*    slot_token = (int*)(ws + take((size_t)NE * NTOK * 4));
  int*    tok_i      = (int*)(ws + take((size_t)NTOK * 4));
  float2* tok_w      = (float2*)(ws + take((size_t)NTOK * 8));
  int2*   inv        = (int2*)(ws + take((size_t)NTOK * 8));
  __hip_bfloat16* w1t  = (__hip_bfloat16*)(ws + take((size_t)NE * DIM * FF * 2));
  size_t stage_off = cur;                         // stage starts at xb
  __hip_bfloat16* xb   = (__hip_bfloat16*)(ws + take((size_t)NTOK * DIM * 2));
  __hip_bfloat16* w3t  = (__hip_bfloat16*)(ws + take((size_t)NE * DIM * FF * 2));
  (void)take((size_t)NTOK * DIM * 2);             // pad so stage fits
  __hip_bfloat16* hbuf = (__hip_bfloat16*)(ws + take((size_t)2 * NTOK * FF * 2));
  __hip_bfloat16* w2t  = w1t;                     // alias (see above)
  float* stage = (float*)(ws + stage_off);        // [2*NTOK][DIM] f32, alias

  hipMemsetAsync(counts, 0, 64, stream);

  k_router<<<NTOK / 4, 256, 0, stream>>>(x, gate_w, logits, tok_i, tok_w, xb);
  k_place<<<NTOK / 256, 256, 0, stream>>>(tok_i, slot_token, counts, inv);
  k_scan<<<1, 64, 0, stream>>>(counts, offsets);
  k_tconv<<<dim3(FF / 32, DIM / 64, NE), 256, 0, stream>>>(w1, w1t, DIM, FF);
  k_tconv<<<dim3(FF / 32, DIM / 64, NE), 256, 0, stream>>>(w3, w3t, DIM, FF);
  k_expert_up<<<dim3(FF / BN, NTOK / BM, NE), 256, 0, stream>>>(
      xb, w1t, w3t, slot_token, counts, offsets, hbuf);
  k_tconv<<<dim3(DIM / 32, FF / 64, NE), 256, 0, stream>>>(w2, w2t, FF, DIM);  // w1t dead
  k_expert_down<<<dim3(DIM / BN, NTOK / BM, NE), 256, 0, stream>>>(
      hbuf, w2t, counts, offsets, stage);
  k_combine<<<NTOK, 256, 0, stream>>>(stage, inv, tok_w, offsets, out);
}